// Round 12
// baseline (183.109 us; speedup 1.0000x reference)
//
#include <hip/hip_runtime.h>
#include <cstdint>

#define BLOCK_SIZE 256
#define NPOS 63   // 9*7 spatial positions per batch

typedef __attribute__((ext_vector_type(8))) short bf16x8;       // 8 bf16, 4 VGPRs
typedef __attribute__((ext_vector_type(4))) float f32x4;
typedef __attribute__((ext_vector_type(4))) unsigned int uint4v;

// DPP 16-lane row reduction (VALU pipe, no LDS) — proven R8-R11.
template <int CTRL>
__device__ __forceinline__ float dpp_add(float v) {
    const int m = __builtin_amdgcn_update_dpp(0, __float_as_int(v), CTRL, 0xF, 0xF, true);
    return v + __int_as_float(m);
}
__device__ __forceinline__ float row16_sum(float v) {
    v = dpp_add<0xB1>(v);   // quad_perm xor1
    v = dpp_add<0x4E>(v);   // quad_perm xor2
    v = dpp_add<0x124>(v);  // row_ror:4
    v = dpp_add<0x128>(v);  // row_ror:8
    return v;
}

// pack hi16(ha):hi16(hb) -> one dword in ONE v_perm_b32 (short0=ha, short1=hb)
__device__ __forceinline__ unsigned pack_hi16(float ha, float hb) {
    return __builtin_amdgcn_perm(__float_as_uint(hb), __float_as_uint(ha), 0x07060302u);
}
__device__ __forceinline__ float lo_part(float h) {
    return h - __uint_as_float(__float_as_uint(h) & 0xFFFF0000u);
}

// R11 -> R12: ONE kernel. Bench-vs-dispatch bookkeeping across R5-R11 shows
// ~35 us overhead PER DISPATCH; R11 spent ~100 us on 3 launches for 82 us of
// kernel time. Fold the W2 hi/lo split into LDS staging (16 fp32/thread,
// ~56 VALU once) and phase-1 (R10-proven wave-per-batch z/c) back in.
// All numerics bit-identical to R11 (same trunc split, 3-product MFMA,
// swizzled LDS, DPP epilogue).
__global__ __launch_bounds__(BLOCK_SIZE) void carnet_fused(
    const float* __restrict__ x,      // (B, 9, 7) flat
    const int*   __restrict__ adj,    // (B, 45)
    const float* __restrict__ ctx,    // (B, 45)
    const float* __restrict__ gcn_W,  // (7, 7)
    const float* __restrict__ gcn_b,  // (7)
    const float* __restrict__ ctx_W,  // (45, 63)
    const float* __restrict__ ctx_b,  // (63)
    const float* __restrict__ W1,     // (64, 2)
    const float* __restrict__ b1,     // (64)
    const float* __restrict__ W2,     // (64, 64)
    const float* __restrict__ b2,     // (64)
    const float* __restrict__ W3,     // (2, 64)
    const float* __restrict__ b3,     // (2)
    float* __restrict__ out)          // (B, 2, 9, 7) flat
{
    __shared__ short sh2h[64 * 64];   // 8192 B, XOR-swizzled (R11-proven)
    __shared__ short sh2l[64 * 64];   // 8192 B

    const int t    = threadIdx.x;
    const int lane = t & 63;

    // ---- staging: W2 fp32 -> hi/lo bf16 planes, swizzled LDS write ----
    // thread t: 16 consecutive floats = row r = t>>2, chunks 2cq, 2cq+1.
    {
        const int r  = t >> 2;
        const int cq = t & 3;
        const float* wsrc = W2 + r * 64 + cq * 16;
        const float4 w0 = ((const float4*)wsrc)[0];
        const float4 w1 = ((const float4*)wsrc)[1];
        const float4 w2v = ((const float4*)wsrc)[2];
        const float4 w3v = ((const float4*)wsrc)[3];
        uint4v hA = { pack_hi16(w0.x, w0.y),  pack_hi16(w0.z, w0.w),
                      pack_hi16(w1.x, w1.y),  pack_hi16(w1.z, w1.w) };
        uint4v hB = { pack_hi16(w2v.x, w2v.y), pack_hi16(w2v.z, w2v.w),
                      pack_hi16(w3v.x, w3v.y), pack_hi16(w3v.z, w3v.w) };
        uint4v lA = { pack_hi16(lo_part(w0.x), lo_part(w0.y)),
                      pack_hi16(lo_part(w0.z), lo_part(w0.w)),
                      pack_hi16(lo_part(w1.x), lo_part(w1.y)),
                      pack_hi16(lo_part(w1.z), lo_part(w1.w)) };
        uint4v lB = { pack_hi16(lo_part(w2v.x), lo_part(w2v.y)),
                      pack_hi16(lo_part(w2v.z), lo_part(w2v.w)),
                      pack_hi16(lo_part(w3v.x), lo_part(w3v.y)),
                      pack_hi16(lo_part(w3v.z), lo_part(w3v.w)) };
        const int sA = ((2 * cq)     ^ (r & 7)) * 8;   // swizzled short offset
        const int sB = ((2 * cq + 1) ^ (r & 7)) * 8;
        *(uint4v*)&sh2h[r * 64 + sA] = hA;
        *(uint4v*)&sh2h[r * 64 + sB] = hB;
        *(uint4v*)&sh2l[r * 64 + sA] = lA;
        *(uint4v*)&sh2l[r * 64 + sB] = lB;
    }

    // ================= PHASE 1: z, c (R10-proven, wave = batch) ==========
    const int b = __builtin_amdgcn_readfirstlane(blockIdx.x * 4 + (t >> 6));
    const int p = lane < 63 ? lane : 62;
    const int n = p / 7;
    const int f = p - n * 7;

    const int* ab = adj + b * 45;
    uint64_t am = 0;
#pragma unroll
    for (int i = 0; i < 45; ++i)
        am |= (uint64_t)(ab[i] != 0) << i;

    float d[9];
#pragma unroll
    for (int i = 0; i < 9; ++i) {
        const int s = 9 * i - (i * (i - 1)) / 2;
        const int w = 8 - i;
        const uint64_t bits = (am >> (s + 1)) & ((1ull << w) - 1ull);
        d[i] = __frsqrt_rn((float)(1 + __popcll(bits)));
    }

    const float* xb = x + b * 63;
    float yv = 0.f;
#pragma unroll
    for (int k = 0; k < 7; ++k)
        yv = fmaf(xb[n * 7 + k], gcn_W[k * 7 + f], yv);

    float zt = 0.f;
    const int snn = 9 * n - (n * (n - 1)) / 2 - n;
#pragma unroll
    for (int m = 0; m < 9; ++m) {
        const float ym = __shfl(yv, m * 7 + f);
        int sh = snn + m;
        sh = sh < 0 ? 0 : sh;
        const bool conn = (m == n) || ((m > n) && ((am >> sh) & 1ull));
        zt = fmaf(conn ? d[m] : 0.f, ym, zt);
    }
    const float zv = fmaf(d[n], zt, gcn_b[f]);

    const float* cb = ctx + b * 45;
    float cacc = ctx_b[p];
#pragma unroll
    for (int q = 0; q < 45; ++q)
        cacc = fmaf(cb[q], ctx_W[q * 63 + p], cacc);
    const float cvv = fmaxf(cacc, 0.f);

    // ================= PHASE 2: MFMA (R11-proven) =======================
    const int cl   = lane & 15;
    const int quad = lane >> 4;
    const int s0 = (quad ^ (cl & 7)) * 16;      // ^64 gives second k-chunk

    float2 wp0[8], wp1[8];
    float  bb0[8], bb1[8];
#pragma unroll
    for (int j = 0; j < 8; ++j) {
        const int o = quad * 8 + j;
        wp0[j] = *(const float2*)(W1 + 2 * o);
        bb0[j] = b1[o];
        wp1[j] = *(const float2*)(W1 + 2 * (o + 32));
        bb1[j] = b1[o + 32];
    }

    const float b2v0 = b2[cl],      b2v1 = b2[16 + cl];
    const float b2v2 = b2[32 + cl], b2v3 = b2[48 + cl];
    const float w3a0 = W3[cl],      w3a1 = W3[16 + cl];
    const float w3a2 = W3[32 + cl], w3a3 = W3[48 + cl];
    const float w3b0 = W3[64 + cl], w3b1 = W3[80 + cl];
    const float w3b2 = W3[96 + cl], w3b3 = W3[112 + cl];
    const float b30 = b3[0], b31 = b3[1];
    float* __restrict__ ob = out + b * 126;

    const char* sh2hB = (const char*)sh2h;
    const char* sh2lB = (const char*)sh2l;

    __syncthreads();   // staging complete before first B read

#pragma unroll 1
    for (int i = 0; i < 4; ++i) {
        const float zm = __shfl(zv,  i * 16 + cl);
        const float cm = __shfl(cvv, i * 16 + cl);

        uint4v ph0, pl0, ph1, pl1;
#pragma unroll
        for (int jj = 0; jj < 4; ++jj) {
            float ha = fmaxf(fmaf(wp0[2*jj].x,   zm, fmaf(wp0[2*jj].y,   cm, bb0[2*jj])),   0.f);
            float hb = fmaxf(fmaf(wp0[2*jj+1].x, zm, fmaf(wp0[2*jj+1].y, cm, bb0[2*jj+1])), 0.f);
            ph0[jj] = pack_hi16(ha, hb);
            pl0[jj] = pack_hi16(lo_part(ha), lo_part(hb));

            ha = fmaxf(fmaf(wp1[2*jj].x,   zm, fmaf(wp1[2*jj].y,   cm, bb1[2*jj])),   0.f);
            hb = fmaxf(fmaf(wp1[2*jj+1].x, zm, fmaf(wp1[2*jj+1].y, cm, bb1[2*jj+1])), 0.f);
            ph1[jj] = pack_hi16(ha, hb);
            pl1[jj] = pack_hi16(lo_part(ha), lo_part(hb));
        }
        const bf16x8 ah0 = __builtin_bit_cast(bf16x8, ph0);
        const bf16x8 al0 = __builtin_bit_cast(bf16x8, pl0);
        const bf16x8 ah1 = __builtin_bit_cast(bf16x8, ph1);
        const bf16x8 al1 = __builtin_bit_cast(bf16x8, pl1);

        f32x4 acc0 = {b2v0, b2v0, b2v0, b2v0};
        f32x4 acc1 = {b2v1, b2v1, b2v1, b2v1};
        f32x4 acc2 = {b2v2, b2v2, b2v2, b2v2};
        f32x4 acc3 = {b2v3, b2v3, b2v3, b2v3};

#define STEP(nt) {                                                                    \
        int bo = cl * 128 + s0;                                                       \
        asm volatile("" : "+v"(bo));                                                  \
        const int bo2 = (cl * 128) | (s0 ^ 64);                                       \
        const bf16x8 bh0 = *(const bf16x8*)(sh2hB + bo  + ((nt) * 2048));             \
        const bf16x8 bh1 = *(const bf16x8*)(sh2hB + bo2 + ((nt) * 2048));             \
        const bf16x8 bl0 = *(const bf16x8*)(sh2lB + bo  + ((nt) * 2048));             \
        const bf16x8 bl1 = *(const bf16x8*)(sh2lB + bo2 + ((nt) * 2048));             \
        acc##nt = __builtin_amdgcn_mfma_f32_16x16x32_bf16(ah0, bh0, acc##nt, 0, 0, 0); \
        acc##nt = __builtin_amdgcn_mfma_f32_16x16x32_bf16(al0, bh0, acc##nt, 0, 0, 0); \
        acc##nt = __builtin_amdgcn_mfma_f32_16x16x32_bf16(ah0, bl0, acc##nt, 0, 0, 0); \
        acc##nt = __builtin_amdgcn_mfma_f32_16x16x32_bf16(ah1, bh1, acc##nt, 0, 0, 0); \
        acc##nt = __builtin_amdgcn_mfma_f32_16x16x32_bf16(al1, bh1, acc##nt, 0, 0, 0); \
        acc##nt = __builtin_amdgcn_mfma_f32_16x16x32_bf16(ah1, bl1, acc##nt, 0, 0, 0); }
        STEP(0) STEP(1) STEP(2) STEP(3)
#undef STEP

        const int ppBase = i * 16 + quad * 4;
#define REDST(reg) {                                                          \
        const float h20 = fmaxf(acc0[reg], 0.f);                              \
        const float h21 = fmaxf(acc1[reg], 0.f);                              \
        const float h22 = fmaxf(acc2[reg], 0.f);                              \
        const float h23 = fmaxf(acc3[reg], 0.f);                              \
        float q0 = fmaf(h23, w3a3, fmaf(h22, w3a2, fmaf(h21, w3a1, h20 * w3a0))); \
        float q1 = fmaf(h23, w3b3, fmaf(h22, w3b2, fmaf(h21, w3b1, h20 * w3b0))); \
        q0 = row16_sum(q0);                                                   \
        q1 = row16_sum(q1);                                                   \
        const int pp = ppBase + (reg);                                        \
        if (cl == 0 && pp < NPOS) {                                           \
            ob[pp]        = q0 + b30;                                         \
            ob[NPOS + pp] = q1 + b31;                                         \
        } }
        REDST(0) REDST(1) REDST(2) REDST(3)
#undef REDST
    }
}

extern "C" void kernel_launch(void* const* d_in, const int* in_sizes, int n_in,
                              void* d_out, int out_size, void* d_ws, size_t ws_size,
                              hipStream_t stream) {
    const float* x     = (const float*)d_in[0];
    const int*   adj   = (const int*)  d_in[1];
    const float* ctx   = (const float*)d_in[2];
    const float* gcn_W = (const float*)d_in[3];
    const float* gcn_b = (const float*)d_in[4];
    const float* ctx_W = (const float*)d_in[5];
    const float* ctx_b = (const float*)d_in[6];
    const float* W1    = (const float*)d_in[7];
    const float* b1    = (const float*)d_in[8];
    const float* W2    = (const float*)d_in[9];
    const float* b2    = (const float*)d_in[10];
    const float* W3    = (const float*)d_in[11];
    const float* b3    = (const float*)d_in[12];
    float* out = (float*)d_out;

    const int nbatch = in_sizes[1] / 45;            // B = 32768
    const int grid = (nbatch + 3) / 4;              // 4 batches (waves) per block
    carnet_fused<<<grid, BLOCK_SIZE, 0, stream>>>(
        x, adj, ctx, gcn_W, gcn_b, ctx_W, ctx_b,
        W1, b1, W2, b2, W3, b3, out);
}

// Round 13
// 178.461 us; speedup vs baseline: 1.0260x; 1.0260x over previous
//
#include <hip/hip_runtime.h>
#include <cstdint>

#define BLOCK_SIZE 256
#define NPOS 63   // 9*7 spatial positions per batch

typedef __attribute__((ext_vector_type(8))) short bf16x8;       // 8 bf16, 4 VGPRs
typedef __attribute__((ext_vector_type(4))) float f32x4;
typedef __attribute__((ext_vector_type(4))) unsigned int uint4v;

// pack hi16(ha):hi16(hb) -> one dword in ONE v_perm_b32 (short0=ha, short1=hb)
__device__ __forceinline__ unsigned pack_hi16(float ha, float hb) {
    return __builtin_amdgcn_perm(__float_as_uint(hb), __float_as_uint(ha), 0x07060302u);
}
__device__ __forceinline__ float lo_part(float h) {
    return h - __uint_as_float(__float_as_uint(h) & 0xFFFF0000u);
}

// R12 -> R13: SWAP MFMA OPERANDS. A/B lane layouts are structurally identical
// (m/n=lane&15, k=quad*8+j), so mfma(W2frag, h1frag, acc) is free and gives
// D[row=channel(quad*4+reg)][col=position(cl)]. The W3 epilogue then becomes
// register-local per position (16 fmax + 32 fma) + 2 shfl_xor per output,
// replacing R12's 16x 16-lane DPP reductions (~460 -> ~230 VALU/thread).
// Same split-bf16 3-product numerics, swizzled LDS, in-kernel W2 split.
__global__ __launch_bounds__(BLOCK_SIZE) void carnet_fused(
    const float* __restrict__ x,      // (B, 9, 7) flat
    const int*   __restrict__ adj,    // (B, 45)
    const float* __restrict__ ctx,    // (B, 45)
    const float* __restrict__ gcn_W,  // (7, 7)
    const float* __restrict__ gcn_b,  // (7)
    const float* __restrict__ ctx_W,  // (45, 63)
    const float* __restrict__ ctx_b,  // (63)
    const float* __restrict__ W1,     // (64, 2)
    const float* __restrict__ b1,     // (64)
    const float* __restrict__ W2,     // (64, 64)
    const float* __restrict__ b2,     // (64)
    const float* __restrict__ W3,     // (2, 64)
    const float* __restrict__ b3,     // (2)
    float* __restrict__ out)          // (B, 2, 9, 7) flat
{
    __shared__ short sh2h[64 * 64];   // 8192 B, XOR-swizzled (R11-proven)
    __shared__ short sh2l[64 * 64];   // 8192 B

    const int t    = threadIdx.x;
    const int lane = t & 63;

    // ---- staging: W2 fp32 -> hi/lo bf16 planes, swizzled LDS write ----
    {
        const int r  = t >> 2;
        const int cq = t & 3;
        const float* wsrc = W2 + r * 64 + cq * 16;
        const float4 w0 = ((const float4*)wsrc)[0];
        const float4 w1 = ((const float4*)wsrc)[1];
        const float4 w2v = ((const float4*)wsrc)[2];
        const float4 w3v = ((const float4*)wsrc)[3];
        uint4v hA = { pack_hi16(w0.x, w0.y),  pack_hi16(w0.z, w0.w),
                      pack_hi16(w1.x, w1.y),  pack_hi16(w1.z, w1.w) };
        uint4v hB = { pack_hi16(w2v.x, w2v.y), pack_hi16(w2v.z, w2v.w),
                      pack_hi16(w3v.x, w3v.y), pack_hi16(w3v.z, w3v.w) };
        uint4v lA = { pack_hi16(lo_part(w0.x), lo_part(w0.y)),
                      pack_hi16(lo_part(w0.z), lo_part(w0.w)),
                      pack_hi16(lo_part(w1.x), lo_part(w1.y)),
                      pack_hi16(lo_part(w1.z), lo_part(w1.w)) };
        uint4v lB = { pack_hi16(lo_part(w2v.x), lo_part(w2v.y)),
                      pack_hi16(lo_part(w2v.z), lo_part(w2v.w)),
                      pack_hi16(lo_part(w3v.x), lo_part(w3v.y)),
                      pack_hi16(lo_part(w3v.z), lo_part(w3v.w)) };
        const int sA = ((2 * cq)     ^ (r & 7)) * 8;
        const int sB = ((2 * cq + 1) ^ (r & 7)) * 8;
        *(uint4v*)&sh2h[r * 64 + sA] = hA;
        *(uint4v*)&sh2h[r * 64 + sB] = hB;
        *(uint4v*)&sh2l[r * 64 + sA] = lA;
        *(uint4v*)&sh2l[r * 64 + sB] = lB;
    }

    // ================= PHASE 1: z, c (R10-proven, wave = batch) ==========
    const int b = __builtin_amdgcn_readfirstlane(blockIdx.x * 4 + (t >> 6));
    const int p = lane < 63 ? lane : 62;
    const int n = p / 7;
    const int f = p - n * 7;

    const int* ab = adj + b * 45;
    uint64_t am = 0;
#pragma unroll
    for (int i = 0; i < 45; ++i)
        am |= (uint64_t)(ab[i] != 0) << i;

    float d[9];
#pragma unroll
    for (int i = 0; i < 9; ++i) {
        const int s = 9 * i - (i * (i - 1)) / 2;
        const int w = 8 - i;
        const uint64_t bits = (am >> (s + 1)) & ((1ull << w) - 1ull);
        d[i] = __frsqrt_rn((float)(1 + __popcll(bits)));
    }

    const float* xb = x + b * 63;
    float yv = 0.f;
#pragma unroll
    for (int k = 0; k < 7; ++k)
        yv = fmaf(xb[n * 7 + k], gcn_W[k * 7 + f], yv);

    float zt = 0.f;
    const int snn = 9 * n - (n * (n - 1)) / 2 - n;
#pragma unroll
    for (int m = 0; m < 9; ++m) {
        const float ym = __shfl(yv, m * 7 + f);
        int sh = snn + m;
        sh = sh < 0 ? 0 : sh;
        const bool conn = (m == n) || ((m > n) && ((am >> sh) & 1ull));
        zt = fmaf(conn ? d[m] : 0.f, ym, zt);
    }
    const float zv = fmaf(d[n], zt, gcn_b[f]);

    // ctx dot with 4 accumulators (shorter dependency chain)
    const float* cb = ctx + b * 45;
    float ca0 = ctx_b[p], ca1 = 0.f, ca2 = 0.f, ca3 = 0.f;
#pragma unroll
    for (int q = 0; q < 44; q += 4) {
        ca0 = fmaf(cb[q],     ctx_W[q * 63 + p],       ca0);
        ca1 = fmaf(cb[q + 1], ctx_W[(q + 1) * 63 + p], ca1);
        ca2 = fmaf(cb[q + 2], ctx_W[(q + 2) * 63 + p], ca2);
        ca3 = fmaf(cb[q + 3], ctx_W[(q + 3) * 63 + p], ca3);
    }
    ca0 = fmaf(cb[44], ctx_W[44 * 63 + p], ca0);
    const float cvv = fmaxf((ca0 + ca1) + (ca2 + ca3), 0.f);

    // ================= PHASE 2: MFMA (operand-swapped) ==================
    const int cl   = lane & 15;       // position within i-tile (B-operand n)
    const int quad = lane >> 4;       // k-octet / C row group (channel)
    const int s0 = (quad ^ (cl & 7)) * 16;

    float2 wp0[8], wp1[8];
    float  bb0[8], bb1[8];
#pragma unroll
    for (int j = 0; j < 8; ++j) {
        const int o = quad * 8 + j;
        wp0[j] = *(const float2*)(W1 + 2 * o);
        bb0[j] = b1[o];
        wp1[j] = *(const float2*)(W1 + 2 * (o + 32));
        bb1[j] = b1[o + 32];
    }

    // Channel-major per-lane constants: this lane's 16 channels are
    // nt*16 + quad*4 + reg  (nt = acc set, reg = acc element).
    const float4 b2q0 = *(const float4*)(b2 + quad * 4);
    const float4 b2q1 = *(const float4*)(b2 + 16 + quad * 4);
    const float4 b2q2 = *(const float4*)(b2 + 32 + quad * 4);
    const float4 b2q3 = *(const float4*)(b2 + 48 + quad * 4);
    const float4 wa0 = *(const float4*)(W3 + quad * 4);
    const float4 wa1 = *(const float4*)(W3 + 16 + quad * 4);
    const float4 wa2 = *(const float4*)(W3 + 32 + quad * 4);
    const float4 wa3 = *(const float4*)(W3 + 48 + quad * 4);
    const float4 wb0 = *(const float4*)(W3 + 64 + quad * 4);
    const float4 wb1 = *(const float4*)(W3 + 80 + quad * 4);
    const float4 wb2 = *(const float4*)(W3 + 96 + quad * 4);
    const float4 wb3 = *(const float4*)(W3 + 112 + quad * 4);
    const float b30 = b3[0], b31 = b3[1];
    float* __restrict__ ob = out + b * 126;

    const char* sh2hB = (const char*)sh2h;
    const char* sh2lB = (const char*)sh2l;

    __syncthreads();   // staging complete before first B read

#pragma unroll 1
    for (int i = 0; i < 4; ++i) {
        const float zm = __shfl(zv,  i * 16 + cl);
        const float cm = __shfl(cvv, i * 16 + cl);

        // h1 fragments (now the MFMA *B* operand; construction unchanged).
        uint4v ph0, pl0, ph1, pl1;
#pragma unroll
        for (int jj = 0; jj < 4; ++jj) {
            float ha = fmaxf(fmaf(wp0[2*jj].x,   zm, fmaf(wp0[2*jj].y,   cm, bb0[2*jj])),   0.f);
            float hb = fmaxf(fmaf(wp0[2*jj+1].x, zm, fmaf(wp0[2*jj+1].y, cm, bb0[2*jj+1])), 0.f);
            ph0[jj] = pack_hi16(ha, hb);
            pl0[jj] = pack_hi16(lo_part(ha), lo_part(hb));

            ha = fmaxf(fmaf(wp1[2*jj].x,   zm, fmaf(wp1[2*jj].y,   cm, bb1[2*jj])),   0.f);
            hb = fmaxf(fmaf(wp1[2*jj+1].x, zm, fmaf(wp1[2*jj+1].y, cm, bb1[2*jj+1])), 0.f);
            ph1[jj] = pack_hi16(ha, hb);
            pl1[jj] = pack_hi16(lo_part(ha), lo_part(hb));
        }
        const bf16x8 ah0 = __builtin_bit_cast(bf16x8, ph0);
        const bf16x8 al0 = __builtin_bit_cast(bf16x8, pl0);
        const bf16x8 ah1 = __builtin_bit_cast(bf16x8, ph1);
        const bf16x8 al1 = __builtin_bit_cast(bf16x8, pl1);

        f32x4 acc0 = {b2q0.x, b2q0.y, b2q0.z, b2q0.w};
        f32x4 acc1 = {b2q1.x, b2q1.y, b2q1.z, b2q1.w};
        f32x4 acc2 = {b2q2.x, b2q2.y, b2q2.z, b2q2.w};
        f32x4 acc3 = {b2q3.x, b2q3.y, b2q3.z, b2q3.w};

        // Operand-swapped: first operand = W2 frag (A, m=channel), second =
        // h1 frag (B, n=position). Products: W2hi*h1hi + W2hi*h1lo + W2lo*h1hi
        // == same 3-term split as R6-R12.
#define STEP(nt) {                                                                    \
        int bo = cl * 128 + s0;                                                       \
        asm volatile("" : "+v"(bo));                                                  \
        const int bo2 = (cl * 128) | (s0 ^ 64);                                       \
        const bf16x8 bh0 = *(const bf16x8*)(sh2hB + bo  + ((nt) * 2048));             \
        const bf16x8 bh1 = *(const bf16x8*)(sh2hB + bo2 + ((nt) * 2048));             \
        const bf16x8 bl0 = *(const bf16x8*)(sh2lB + bo  + ((nt) * 2048));             \
        const bf16x8 bl1 = *(const bf16x8*)(sh2lB + bo2 + ((nt) * 2048));             \
        acc##nt = __builtin_amdgcn_mfma_f32_16x16x32_bf16(bh0, ah0, acc##nt, 0, 0, 0); \
        acc##nt = __builtin_amdgcn_mfma_f32_16x16x32_bf16(bh0, al0, acc##nt, 0, 0, 0); \
        acc##nt = __builtin_amdgcn_mfma_f32_16x16x32_bf16(bl0, ah0, acc##nt, 0, 0, 0); \
        acc##nt = __builtin_amdgcn_mfma_f32_16x16x32_bf16(bh1, ah1, acc##nt, 0, 0, 0); \
        acc##nt = __builtin_amdgcn_mfma_f32_16x16x32_bf16(bh1, al1, acc##nt, 0, 0, 0); \
        acc##nt = __builtin_amdgcn_mfma_f32_16x16x32_bf16(bl1, ah1, acc##nt, 0, 0, 0); }
        STEP(0) STEP(1) STEP(2) STEP(3)
#undef STEP

        // Epilogue (channel-major): lane holds 16 channels of position
        // pos = i*16+cl. Register-local relu+W3 dot, then sum over 4 quads.
        float q0, q1;
        {
            float h;
            h = fmaxf(acc0[0], 0.f); q0 = h * wa0.x;            q1 = h * wb0.x;
            h = fmaxf(acc0[1], 0.f); q0 = fmaf(h, wa0.y, q0);   q1 = fmaf(h, wb0.y, q1);
            h = fmaxf(acc0[2], 0.f); q0 = fmaf(h, wa0.z, q0);   q1 = fmaf(h, wb0.z, q1);
            h = fmaxf(acc0[3], 0.f); q0 = fmaf(h, wa0.w, q0);   q1 = fmaf(h, wb0.w, q1);
            h = fmaxf(acc1[0], 0.f); q0 = fmaf(h, wa1.x, q0);   q1 = fmaf(h, wb1.x, q1);
            h = fmaxf(acc1[1], 0.f); q0 = fmaf(h, wa1.y, q0);   q1 = fmaf(h, wb1.y, q1);
            h = fmaxf(acc1[2], 0.f); q0 = fmaf(h, wa1.z, q0);   q1 = fmaf(h, wb1.z, q1);
            h = fmaxf(acc1[3], 0.f); q0 = fmaf(h, wa1.w, q0);   q1 = fmaf(h, wb1.w, q1);
            h = fmaxf(acc2[0], 0.f); q0 = fmaf(h, wa2.x, q0);   q1 = fmaf(h, wb2.x, q1);
            h = fmaxf(acc2[1], 0.f); q0 = fmaf(h, wa2.y, q0);   q1 = fmaf(h, wb2.y, q1);
            h = fmaxf(acc2[2], 0.f); q0 = fmaf(h, wa2.z, q0);   q1 = fmaf(h, wb2.z, q1);
            h = fmaxf(acc2[3], 0.f); q0 = fmaf(h, wa2.w, q0);   q1 = fmaf(h, wb2.w, q1);
            h = fmaxf(acc3[0], 0.f); q0 = fmaf(h, wa3.x, q0);   q1 = fmaf(h, wb3.x, q1);
            h = fmaxf(acc3[1], 0.f); q0 = fmaf(h, wa3.y, q0);   q1 = fmaf(h, wb3.y, q1);
            h = fmaxf(acc3[2], 0.f); q0 = fmaf(h, wa3.z, q0);   q1 = fmaf(h, wb3.z, q1);
            h = fmaxf(acc3[3], 0.f); q0 = fmaf(h, wa3.w, q0);   q1 = fmaf(h, wb3.w, q1);
        }
        q0 += __shfl_xor(q0, 16); q0 += __shfl_xor(q0, 32);
        q1 += __shfl_xor(q1, 16); q1 += __shfl_xor(q1, 32);

        const int pp = i * 16 + cl;
        if (quad == 0 && pp < NPOS) {
            ob[pp]        = q0 + b30;
            ob[NPOS + pp] = q1 + b31;
        }
    }
}

extern "C" void kernel_launch(void* const* d_in, const int* in_sizes, int n_in,
                              void* d_out, int out_size, void* d_ws, size_t ws_size,
                              hipStream_t stream) {
    const float* x     = (const float*)d_in[0];
    const int*   adj   = (const int*)  d_in[1];
    const float* ctx   = (const float*)d_in[2];
    const float* gcn_W = (const float*)d_in[3];
    const float* gcn_b = (const float*)d_in[4];
    const float* ctx_W = (const float*)d_in[5];
    const float* ctx_b = (const float*)d_in[6];
    const float* W1    = (const float*)d_in[7];
    const float* b1    = (const float*)d_in[8];
    const float* W2    = (const float*)d_in[9];
    const float* b2    = (const float*)d_in[10];
    const float* W3    = (const float*)d_in[11];
    const float* b3    = (const float*)d_in[12];
    float* out = (float*)d_out;

    const int nbatch = in_sizes[1] / 45;            // B = 32768
    const int grid = (nbatch + 3) / 4;              // 4 batches (waves) per block
    carnet_fused<<<grid, BLOCK_SIZE, 0, stream>>>(
        x, adj, ctx, gcn_W, gcn_b, ctx_W, ctx_b,
        W1, b1, W2, b2, W3, b3, out);
}

// Round 14
// 174.154 us; speedup vs baseline: 1.0514x; 1.0247x over previous
//
#include <hip/hip_runtime.h>
#include <cstdint>

#define BLOCK_SIZE 256
#define NPOS 63   // 9*7 spatial positions per batch

typedef __attribute__((ext_vector_type(8))) short bf16x8;       // 8 bf16, 4 VGPRs
typedef __attribute__((ext_vector_type(4))) float f32x4;
typedef __attribute__((ext_vector_type(4))) unsigned int uint4v;

// pack hi16(ha):hi16(hb) -> one dword in ONE v_perm_b32 (short0=ha, short1=hb)
__device__ __forceinline__ unsigned pack_hi16(float ha, float hb) {
    return __builtin_amdgcn_perm(__float_as_uint(hb), __float_as_uint(ha), 0x07060302u);
}
__device__ __forceinline__ float lo_part(float h) {
    return h - __uint_as_float(__float_as_uint(h) & 0xFFFF0000u);
}
// round-to-nearest-even bf16 bits (returned in low 16)
__device__ __forceinline__ unsigned rne_bf16(float a) {
    const unsigned u = __float_as_uint(a);
    return (u + 0x7FFFu + ((u >> 16) & 1u)) >> 16;
}

// R13 -> R14: 2-PRODUCT SPLIT. W2 rounded ONCE to bf16 (RNE, error 2^-9 rel
// => ~0.004 abs on out, under the 0.0078 reference floor); h1 keeps the exact
// Dekker hi/lo split. out = W2bf16*h1hi + W2bf16*h1lo.
//  - MFMA/wave 96 -> 64, LDS B-reads 64 -> 32 (per-CU LDS pipe was 47% of
//    runtime in R13), LDS 16 KB -> 8 KB, staging halves.
// Everything else (phase-1 wave-per-batch, swizzled LDS, operand-swapped
// MFMA, channel-major epilogue) is R13-proven code unchanged.
__global__ __launch_bounds__(BLOCK_SIZE) void carnet_fused(
    const float* __restrict__ x,      // (B, 9, 7) flat
    const int*   __restrict__ adj,    // (B, 45)
    const float* __restrict__ ctx,    // (B, 45)
    const float* __restrict__ gcn_W,  // (7, 7)
    const float* __restrict__ gcn_b,  // (7)
    const float* __restrict__ ctx_W,  // (45, 63)
    const float* __restrict__ ctx_b,  // (63)
    const float* __restrict__ W1,     // (64, 2)
    const float* __restrict__ b1,     // (64)
    const float* __restrict__ W2,     // (64, 64)
    const float* __restrict__ b2,     // (64)
    const float* __restrict__ W3,     // (2, 64)
    const float* __restrict__ b3,     // (2)
    float* __restrict__ out)          // (B, 2, 9, 7) flat
{
    __shared__ short sh2b[64 * 64];   // 8192 B, XOR-swizzled, RNE bf16 of W2

    const int t    = threadIdx.x;
    const int lane = t & 63;

    // ---- staging: W2 fp32 -> RNE bf16 plane, swizzled LDS write ----
    {
        const int r  = t >> 2;
        const int cq = t & 3;
        const float* wsrc = W2 + r * 64 + cq * 16;
        const float4 w0 = ((const float4*)wsrc)[0];
        const float4 w1 = ((const float4*)wsrc)[1];
        const float4 w2v = ((const float4*)wsrc)[2];
        const float4 w3v = ((const float4*)wsrc)[3];
        uint4v hA = { rne_bf16(w0.x)  | (rne_bf16(w0.y)  << 16),
                      rne_bf16(w0.z)  | (rne_bf16(w0.w)  << 16),
                      rne_bf16(w1.x)  | (rne_bf16(w1.y)  << 16),
                      rne_bf16(w1.z)  | (rne_bf16(w1.w)  << 16) };
        uint4v hB = { rne_bf16(w2v.x) | (rne_bf16(w2v.y) << 16),
                      rne_bf16(w2v.z) | (rne_bf16(w2v.w) << 16),
                      rne_bf16(w3v.x) | (rne_bf16(w3v.y) << 16),
                      rne_bf16(w3v.z) | (rne_bf16(w3v.w) << 16) };
        const int sA = ((2 * cq)     ^ (r & 7)) * 8;
        const int sB = ((2 * cq + 1) ^ (r & 7)) * 8;
        *(uint4v*)&sh2b[r * 64 + sA] = hA;
        *(uint4v*)&sh2b[r * 64 + sB] = hB;
    }

    // ================= PHASE 1: z, c (R10-proven, wave = batch) ==========
    const int b = __builtin_amdgcn_readfirstlane(blockIdx.x * 4 + (t >> 6));
    const int p = lane < 63 ? lane : 62;
    const int n = p / 7;
    const int f = p - n * 7;

    const int* ab = adj + b * 45;
    uint64_t am = 0;
#pragma unroll
    for (int i = 0; i < 45; ++i)
        am |= (uint64_t)(ab[i] != 0) << i;

    float d[9];
#pragma unroll
    for (int i = 0; i < 9; ++i) {
        const int s = 9 * i - (i * (i - 1)) / 2;
        const int w = 8 - i;
        const uint64_t bits = (am >> (s + 1)) & ((1ull << w) - 1ull);
        d[i] = __frsqrt_rn((float)(1 + __popcll(bits)));
    }

    const float* xb = x + b * 63;
    float yv = 0.f;
#pragma unroll
    for (int k = 0; k < 7; ++k)
        yv = fmaf(xb[n * 7 + k], gcn_W[k * 7 + f], yv);

    float zt = 0.f;
    const int snn = 9 * n - (n * (n - 1)) / 2 - n;
#pragma unroll
    for (int m = 0; m < 9; ++m) {
        const float ym = __shfl(yv, m * 7 + f);
        int sh = snn + m;
        sh = sh < 0 ? 0 : sh;
        const bool conn = (m == n) || ((m > n) && ((am >> sh) & 1ull));
        zt = fmaf(conn ? d[m] : 0.f, ym, zt);
    }
    const float zv = fmaf(d[n], zt, gcn_b[f]);

    // ctx dot with 4 accumulators (shorter dependency chain)
    const float* cb = ctx + b * 45;
    float ca0 = ctx_b[p], ca1 = 0.f, ca2 = 0.f, ca3 = 0.f;
#pragma unroll
    for (int q = 0; q < 44; q += 4) {
        ca0 = fmaf(cb[q],     ctx_W[q * 63 + p],       ca0);
        ca1 = fmaf(cb[q + 1], ctx_W[(q + 1) * 63 + p], ca1);
        ca2 = fmaf(cb[q + 2], ctx_W[(q + 2) * 63 + p], ca2);
        ca3 = fmaf(cb[q + 3], ctx_W[(q + 3) * 63 + p], ca3);
    }
    ca0 = fmaf(cb[44], ctx_W[44 * 63 + p], ca0);
    const float cvv = fmaxf((ca0 + ca1) + (ca2 + ca3), 0.f);

    // ================= PHASE 2: MFMA (operand-swapped, 2-product) =======
    const int cl   = lane & 15;       // position within i-tile (B-operand n)
    const int quad = lane >> 4;       // k-octet / C row group (channel)
    const int s0 = (quad ^ (cl & 7)) * 16;

    float2 wp0[8], wp1[8];
    float  bb0[8], bb1[8];
#pragma unroll
    for (int j = 0; j < 8; ++j) {
        const int o = quad * 8 + j;
        wp0[j] = *(const float2*)(W1 + 2 * o);
        bb0[j] = b1[o];
        wp1[j] = *(const float2*)(W1 + 2 * (o + 32));
        bb1[j] = b1[o + 32];
    }

    const float4 b2q0 = *(const float4*)(b2 + quad * 4);
    const float4 b2q1 = *(const float4*)(b2 + 16 + quad * 4);
    const float4 b2q2 = *(const float4*)(b2 + 32 + quad * 4);
    const float4 b2q3 = *(const float4*)(b2 + 48 + quad * 4);
    const float4 wa0 = *(const float4*)(W3 + quad * 4);
    const float4 wa1 = *(const float4*)(W3 + 16 + quad * 4);
    const float4 wa2 = *(const float4*)(W3 + 32 + quad * 4);
    const float4 wa3 = *(const float4*)(W3 + 48 + quad * 4);
    const float4 wb0 = *(const float4*)(W3 + 64 + quad * 4);
    const float4 wb1 = *(const float4*)(W3 + 80 + quad * 4);
    const float4 wb2 = *(const float4*)(W3 + 96 + quad * 4);
    const float4 wb3 = *(const float4*)(W3 + 112 + quad * 4);
    const float b30 = b3[0], b31 = b3[1];
    float* __restrict__ ob = out + b * 126;

    const char* sh2bB = (const char*)sh2b;

    __syncthreads();   // staging complete before first B read

#pragma unroll 1
    for (int i = 0; i < 4; ++i) {
        const float zm = __shfl(zv,  i * 16 + cl);
        const float cm = __shfl(cvv, i * 16 + cl);

        // h1 fragments (MFMA B operand): exact Dekker hi/lo split.
        uint4v ph0, pl0, ph1, pl1;
#pragma unroll
        for (int jj = 0; jj < 4; ++jj) {
            float ha = fmaxf(fmaf(wp0[2*jj].x,   zm, fmaf(wp0[2*jj].y,   cm, bb0[2*jj])),   0.f);
            float hb = fmaxf(fmaf(wp0[2*jj+1].x, zm, fmaf(wp0[2*jj+1].y, cm, bb0[2*jj+1])), 0.f);
            ph0[jj] = pack_hi16(ha, hb);
            pl0[jj] = pack_hi16(lo_part(ha), lo_part(hb));

            ha = fmaxf(fmaf(wp1[2*jj].x,   zm, fmaf(wp1[2*jj].y,   cm, bb1[2*jj])),   0.f);
            hb = fmaxf(fmaf(wp1[2*jj+1].x, zm, fmaf(wp1[2*jj+1].y, cm, bb1[2*jj+1])), 0.f);
            ph1[jj] = pack_hi16(ha, hb);
            pl1[jj] = pack_hi16(lo_part(ha), lo_part(hb));
        }
        const bf16x8 ah0 = __builtin_bit_cast(bf16x8, ph0);
        const bf16x8 al0 = __builtin_bit_cast(bf16x8, pl0);
        const bf16x8 ah1 = __builtin_bit_cast(bf16x8, ph1);
        const bf16x8 al1 = __builtin_bit_cast(bf16x8, pl1);

        f32x4 acc0 = {b2q0.x, b2q0.y, b2q0.z, b2q0.w};
        f32x4 acc1 = {b2q1.x, b2q1.y, b2q1.z, b2q1.w};
        f32x4 acc2 = {b2q2.x, b2q2.y, b2q2.z, b2q2.w};
        f32x4 acc3 = {b2q3.x, b2q3.y, b2q3.z, b2q3.w};

        // A = W2 bf16 frag (LDS, 2 reads/STEP), B = h1 hi/lo (4 MFMAs/STEP).
#define STEP(nt) {                                                                    \
        int bo = cl * 128 + s0;                                                       \
        asm volatile("" : "+v"(bo));                                                  \
        const int bo2 = (cl * 128) | (s0 ^ 64);                                       \
        const bf16x8 wf0 = *(const bf16x8*)(sh2bB + bo  + ((nt) * 2048));             \
        const bf16x8 wf1 = *(const bf16x8*)(sh2bB + bo2 + ((nt) * 2048));             \
        acc##nt = __builtin_amdgcn_mfma_f32_16x16x32_bf16(wf0, ah0, acc##nt, 0, 0, 0); \
        acc##nt = __builtin_amdgcn_mfma_f32_16x16x32_bf16(wf0, al0, acc##nt, 0, 0, 0); \
        acc##nt = __builtin_amdgcn_mfma_f32_16x16x32_bf16(wf1, ah1, acc##nt, 0, 0, 0); \
        acc##nt = __builtin_amdgcn_mfma_f32_16x16x32_bf16(wf1, al1, acc##nt, 0, 0, 0); }
        STEP(0) STEP(1) STEP(2) STEP(3)
#undef STEP

        // Epilogue (channel-major, R13-proven): register-local relu + W3 dot,
        // then sum over 4 quads via shfl_xor(16/32); quad 0 stores.
        float q0, q1;
        {
            float h;
            h = fmaxf(acc0[0], 0.f); q0 = h * wa0.x;            q1 = h * wb0.x;
            h = fmaxf(acc0[1], 0.f); q0 = fmaf(h, wa0.y, q0);   q1 = fmaf(h, wb0.y, q1);
            h = fmaxf(acc0[2], 0.f); q0 = fmaf(h, wa0.z, q0);   q1 = fmaf(h, wb0.z, q1);
            h = fmaxf(acc0[3], 0.f); q0 = fmaf(h, wa0.w, q0);   q1 = fmaf(h, wb0.w, q1);
            h = fmaxf(acc1[0], 0.f); q0 = fmaf(h, wa1.x, q0);   q1 = fmaf(h, wb1.x, q1);
            h = fmaxf(acc1[1], 0.f); q0 = fmaf(h, wa1.y, q0);   q1 = fmaf(h, wb1.y, q1);
            h = fmaxf(acc1[2], 0.f); q0 = fmaf(h, wa1.z, q0);   q1 = fmaf(h, wb1.z, q1);
            h = fmaxf(acc1[3], 0.f); q0 = fmaf(h, wa1.w, q0);   q1 = fmaf(h, wb1.w, q1);
            h = fmaxf(acc2[0], 0.f); q0 = fmaf(h, wa2.x, q0);   q1 = fmaf(h, wb2.x, q1);
            h = fmaxf(acc2[1], 0.f); q0 = fmaf(h, wa2.y, q0);   q1 = fmaf(h, wb2.y, q1);
            h = fmaxf(acc2[2], 0.f); q0 = fmaf(h, wa2.z, q0);   q1 = fmaf(h, wb2.z, q1);
            h = fmaxf(acc2[3], 0.f); q0 = fmaf(h, wa2.w, q0);   q1 = fmaf(h, wb2.w, q1);
            h = fmaxf(acc3[0], 0.f); q0 = fmaf(h, wa3.x, q0);   q1 = fmaf(h, wb3.x, q1);
            h = fmaxf(acc3[1], 0.f); q0 = fmaf(h, wa3.y, q0);   q1 = fmaf(h, wb3.y, q1);
            h = fmaxf(acc3[2], 0.f); q0 = fmaf(h, wa3.z, q0);   q1 = fmaf(h, wb3.z, q1);
            h = fmaxf(acc3[3], 0.f); q0 = fmaf(h, wa3.w, q0);   q1 = fmaf(h, wb3.w, q1);
        }
        q0 += __shfl_xor(q0, 16); q0 += __shfl_xor(q0, 32);
        q1 += __shfl_xor(q1, 16); q1 += __shfl_xor(q1, 32);

        const int pp = i * 16 + cl;
        if (quad == 0 && pp < NPOS) {
            ob[pp]        = q0 + b30;
            ob[NPOS + pp] = q1 + b31;
        }
    }
}

extern "C" void kernel_launch(void* const* d_in, const int* in_sizes, int n_in,
                              void* d_out, int out_size, void* d_ws, size_t ws_size,
                              hipStream_t stream) {
    const float* x     = (const float*)d_in[0];
    const int*   adj   = (const int*)  d_in[1];
    const float* ctx   = (const float*)d_in[2];
    const float* gcn_W = (const float*)d_in[3];
    const float* gcn_b = (const float*)d_in[4];
    const float* ctx_W = (const float*)d_in[5];
    const float* ctx_b = (const float*)d_in[6];
    const float* W1    = (const float*)d_in[7];
    const float* b1    = (const float*)d_in[8];
    const float* W2    = (const float*)d_in[9];
    const float* b2    = (const float*)d_in[10];
    const float* W3    = (const float*)d_in[11];
    const float* b3    = (const float*)d_in[12];
    float* out = (float*)d_out;

    const int nbatch = in_sizes[1] / 45;            // B = 32768
    const int grid = (nbatch + 3) / 4;              // 4 batches (waves) per block
    carnet_fused<<<grid, BLOCK_SIZE, 0, stream>>>(
        x, adj, ctx, gcn_W, gcn_b, ctx_W, ctx_b,
        W1, b1, W2, b2, W3, b3, out);
}